// Round 1
// baseline (137.211 us; speedup 1.0000x reference)
//
#include <hip/hip_runtime.h>
#include <stdint.h>

#define DMAX 80

// ---------------------------------------------------------------------------
// Setup kernel:
//  - thread (0,0): detect mask dtype (bool8 / int32 / float32) using known m,
//    compact selected indices into idx_out[0..m).
//  - all threads (grid-stride over pair ranks p in [0,P), P = m(m+1)/2):
//    build the column table: table[c] = i | j<<8 | k<<16 where the output
//    column c is xsel[i]*xsel[j]*xsel[k]; unused slots point to sentinel
//    index m (value 1.0f).  Column order matches
//    combinations_with_replacement lex order:
//      [0,m)            : order-1, (i, m, m)
//      [m, m+P)         : order-2 pair rank p -> (i, j, m)
//      [m+P, T)         : order-3, for pair (i,j) a run over k in [j,m)
// ---------------------------------------------------------------------------
__global__ void maskde_setup(const void* __restrict__ mask_raw, int m,
                             int* __restrict__ idx_out,
                             uint32_t* __restrict__ table, int P) {
    int tid = blockIdx.x * blockDim.x + threadIdx.x;
    if (tid == 0) {
        const uint8_t* b8  = (const uint8_t*)mask_raw;
        const int*     b32 = (const int*)mask_raw;
        const float*   bf  = (const float*)mask_raw;
        // try uint8/bool view
        int cnt = 0; bool ok = true;
        for (int i = 0; i < DMAX; ++i) { uint8_t v = b8[i]; if (v > 1) ok = false; cnt += (v != 0); }
        int mode;
        if (ok && cnt == m) {
            mode = 0;
        } else {
            cnt = 0; ok = true;
            for (int i = 0; i < DMAX; ++i) { int v = b32[i]; if (v != 0 && v != 1) ok = false; cnt += (v != 0); }
            mode = (ok && cnt == m) ? 1 : 2;   // 2 = float fallback
        }
        int k = 0;
        for (int i = 0; i < DMAX && k < m; ++i) {
            bool on = (mode == 0) ? (b8[i] != 0)
                    : (mode == 1) ? (b32[i] != 0)
                                  : (bf[i] != 0.0f);
            if (on) idx_out[k++] = i;
        }
    }

    int stride = gridDim.x * blockDim.x;
    for (int p = tid; p < P; p += stride) {
        // unrank pair rank p -> (i, j), i <= j, lex order
        int rem = p, i = 0;
        while (rem >= m - i) { rem -= (m - i); ++i; }
        int j = i + rem;

        if (p < m) {   // order-1 entries
            table[p] = (uint32_t)p | ((uint32_t)m << 8) | ((uint32_t)m << 16);
        }
        // order-2 entry at rank p
        table[m + p] = (uint32_t)i | ((uint32_t)j << 8) | ((uint32_t)m << 16);

        // order-3 run for this (i,j): k in [j, m)
        // S(i)   = # triples with first index < i
        //        = (m(m+1)(m+2) - (m-i)(m-i+1)(m-i+2)) / 6
        // R(i,j) = # triples (i, j', *) with j' in [i, j)
        //        = ((m-i) + (m-j+1)) * (j-i) / 2
        int mi = m - i;
        long long Si  = ((long long)m * (m + 1) * (m + 2)
                       - (long long)mi * (mi + 1) * (mi + 2)) / 6;
        int Rij = ((m - i) + (m - j + 1)) * (j - i) / 2;
        uint32_t* t3 = table + m + P + Si + Rij;
        uint32_t packed_ij = (uint32_t)i | ((uint32_t)j << 8);
        for (int k3 = j; k3 < m; ++k3) {
            t3[k3 - j] = packed_ij | ((uint32_t)k3 << 16);
        }
    }
}

// ---------------------------------------------------------------------------
// Main kernel: one block per row.  Stage the m selected x values (+ sentinel
// 1.0f) into LDS, then stream all T output columns with float4 stores.
// ---------------------------------------------------------------------------
__global__ __launch_bounds__(256) void
maskde_expand(const float* __restrict__ x, const int* __restrict__ idx,
              const uint32_t* __restrict__ table, float* __restrict__ out,
              int m, int T) {
    __shared__ float xls[DMAX + 1];
    const int row = blockIdx.x;
    const int tid = threadIdx.x;

    if (tid <= m) {
        xls[tid] = (tid < m) ? x[row * DMAX + idx[tid]] : 1.0f;
    }
    __syncthreads();

    float* orow = out + (size_t)row * (size_t)T;

    // scalar prologue until 16B alignment (T is odd in general)
    uintptr_t addr = (uintptr_t)orow;
    int k0 = (int)(((16 - (addr & 15)) & 15) >> 2);
    if (k0 > T) k0 = T;
    if (tid < k0) {
        uint32_t e = table[tid];
        orow[tid] = xls[e & 0xFF] * xls[(e >> 8) & 0xFF] * xls[(e >> 16) & 0xFF];
    }

    const int nv = (T - k0) >> 2;          // float4 count
    const uint32_t* tb = table + k0;
    float4* ov = (float4*)(orow + k0);
    for (int v = tid; v < nv; v += 256) {
        uint32_t e0 = tb[4 * v + 0];
        uint32_t e1 = tb[4 * v + 1];
        uint32_t e2 = tb[4 * v + 2];
        uint32_t e3 = tb[4 * v + 3];
        float4 r;
        r.x = xls[e0 & 0xFF] * xls[(e0 >> 8) & 0xFF] * xls[(e0 >> 16) & 0xFF];
        r.y = xls[e1 & 0xFF] * xls[(e1 >> 8) & 0xFF] * xls[(e1 >> 16) & 0xFF];
        r.z = xls[e2 & 0xFF] * xls[(e2 >> 8) & 0xFF] * xls[(e2 >> 16) & 0xFF];
        r.w = xls[e3 & 0xFF] * xls[(e3 >> 8) & 0xFF] * xls[(e3 >> 16) & 0xFF];
        ov[v] = r;
    }

    // scalar tail
    int tstart = k0 + 4 * nv;
    int c = tstart + tid;
    if (c < T) {
        uint32_t e = table[c];
        orow[c] = xls[e & 0xFF] * xls[(e >> 8) & 0xFF] * xls[(e >> 16) & 0xFF];
    }
}

extern "C" void kernel_launch(void* const* d_in, const int* in_sizes, int n_in,
                              void* d_out, int out_size, void* d_ws, size_t ws_size,
                              hipStream_t stream) {
    const float* x    = (const float*)d_in[0];
    const void*  mask = d_in[1];
    float*       out  = (float*)d_out;

    int rows = in_sizes[0] / DMAX;
    if (rows <= 0 || out_size <= 0) return;
    long long T = (long long)out_size / rows;

    // recover m from T(m) = m + m(m+1)/2 + m(m+1)(m+2)/6
    int m = -1;
    for (int mm = 0; mm <= DMAX; ++mm) {
        long long t = (long long)mm
                    + (long long)mm * (mm + 1) / 2
                    + (long long)mm * (mm + 1) * (mm + 2) / 6;
        if (t == T) { m = mm; break; }
    }
    if (m <= 0) return;

    int* idx        = (int*)d_ws;
    uint32_t* table = (uint32_t*)d_ws + 128;
    int P = m * (m + 1) / 2;

    int sblocks = (P + 255) / 256;
    if (sblocks < 1) sblocks = 1;
    maskde_setup<<<sblocks, 256, 0, stream>>>(mask, m, idx, table, P);
    maskde_expand<<<rows, 256, 0, stream>>>(x, idx, table, out, m, (int)T);
}